// Round 9
// baseline (50.606 us; speedup 1.0000x reference)
//
#include <hip/hip_runtime.h>
#include <hip/hip_bf16.h>
#include <stdint.h>

// Quanvolution + linear(784->10) + log_softmax via MFMA, B=65536, fp32 in/out.
// R8: R7's VMEM-floor structure, but each wave owns TWO 16-row MFMA tiles
// (32 rows) sharing one set of preloaded W fragments.
//  - 2048 blocks x 128 thr (2 waves: K-half kh=0/1). Block owns 32 rows.
//  - per K-block: 4 independent float4 loads -> 2 independent MFMA chains
//    (2x MLP per wave); total waves 8192 -> 4096, VMEM instrs -17%.
//  - W frags (14 x short8 = 56 VGPR) preloaded once, shared by both tiles.
//  - no branches / no in-loop LDS; 1 barrier (kh merge).
// K-permutation identical to R7 (validated, absmax 0.031):
//  kb = 2*pr + half; lane (r16,kg) owns 8 contiguous floats; pads hit W=0.

typedef __attribute__((ext_vector_type(8))) short short8;
typedef __attribute__((ext_vector_type(4))) float f32x4;

// ---- pre-kernel: bake W -> bf16 frags ws[kb][lane][e], 28 KB ----
__global__ void quanv_wprep_kernel(const float* __restrict__ Wm,
                                   uint32_t* __restrict__ ws) {
    const int idx = blockIdx.x * 256 + threadIdx.x;   // [0, 7168)
    if (idx >= 7168) return;
    const int kb   = idx >> 8;      // 0..27
    const int rem  = idx & 255;
    const int l    = rem >> 2;      // lane 0..63
    const int d    = rem & 3;       // u32 pair -> e = 2d, 2d+1
    const int n    = l & 15;
    const int kg   = l >> 4;
    const int pr   = kb >> 1;
    const int half = kb & 1;
    uint32_t outv = 0;
    if (n < 10) {
        uint32_t hv[2];
#pragma unroll
        for (int d2 = 0; d2 < 2; ++d2) {
            const int e  = 2 * d + d2;
            const int fi = ((kg >= 2) ? 2 : 0) + (e & 1);
            int j; bool pad = false;
            if (half == 0) {
                j = 4 * (kg & 1) + (e >> 1);
            } else if ((kg & 1) == 0) {
                j = 8 + (e >> 1);
            } else {
                pad = (e < 4);
                const int e4 = (e >= 4) ? (e - 4) : 0;
                j = 12 + (e4 >> 1);
            }
            const float v = pad ? 0.f : Wm[n * 784 + (pr * 14 + j) * 4 + fi];
            hv[d2] = (uint32_t)__bfloat16_as_ushort(__float2bfloat16(v));
        }
        outv = hv[0] | (hv[1] << 16);
    }
    ws[idx] = outv;
}

// ---- 8 features from two adjacent float4s ----
#define FEAT8(VA, VB, A) do {                                                 \
    { const float ce=__cosf((VA).x), co=__cosf((VA).y);                       \
      (A)[0]=(short)__bfloat16_as_ushort(__float2bfloat16(ce + (VA).x));      \
      (A)[1]=(short)__bfloat16_as_ushort(__float2bfloat16(fmaf(ce,co,(VA).y)));}\
    { const float ce=__cosf((VA).z), co=__cosf((VA).w);                       \
      (A)[2]=(short)__bfloat16_as_ushort(__float2bfloat16(ce + (VA).z));      \
      (A)[3]=(short)__bfloat16_as_ushort(__float2bfloat16(fmaf(ce,co,(VA).w)));}\
    { const float ce=__cosf((VB).x), co=__cosf((VB).y);                       \
      (A)[4]=(short)__bfloat16_as_ushort(__float2bfloat16(ce + (VB).x));      \
      (A)[5]=(short)__bfloat16_as_ushort(__float2bfloat16(fmaf(ce,co,(VB).y)));}\
    { const float ce=__cosf((VB).z), co=__cosf((VB).w);                       \
      (A)[6]=(short)__bfloat16_as_ushort(__float2bfloat16(ce + (VB).z));      \
      (A)[7]=(short)__bfloat16_as_ushort(__float2bfloat16(fmaf(ce,co,(VB).w)));}\
} while (0)

// ---- one K-block, both tiles: 4 loads -> 2 MFMA (shared W frag) ----
#define QKB2(PA, PB, IMM, WF) do {                                            \
    const float4 vaA = *(const float4*)((PA) + (IMM));                        \
    const float4 vbA = *(const float4*)((PA) + (IMM) + 4);                    \
    const float4 vaB = *(const float4*)((PB) + (IMM));                        \
    const float4 vbB = *(const float4*)((PB) + (IMM) + 4);                    \
    short8 aA, aB;                                                            \
    FEAT8(vaA, vbA, aA);                                                      \
    FEAT8(vaB, vbB, aB);                                                      \
    accA = __builtin_amdgcn_mfma_f32_16x16x32_bf16(aA, (WF), accA, 0, 0, 0);  \
    accB = __builtin_amdgcn_mfma_f32_16x16x32_bf16(aB, (WF), accB, 0, 0, 0);  \
} while (0)

__global__ __launch_bounds__(128, 4)
void quanv_mfma4_kernel(const float* __restrict__ x,
                        const char* __restrict__ wsb,   // bf16 frags [28][64][8]
                        const float* __restrict__ bias,
                        float* __restrict__ out) {
    __shared__ f32x4 red[2][64];   // 2 KB: kh=1 accumulators (tile A, B)

    const int t   = threadIdx.x;
    const int l   = t & 63;
    const int kh  = __builtin_amdgcn_readfirstlane(t >> 6);   // K-half 0/1
    const int r16 = l & 15;        // A-row (x row) / B-col (class)
    const int kg  = l >> 4;        // k-group 0..3
    const int rowA = blockIdx.x * 32 + r16;       // tile A row
    const float* xrA = x + (size_t)rowA * 784 + kh * 392;
    const float* xrB = xrA + 16 * 784;            // tile B row (+16)

    // per-lane contiguous 8-float base offsets (same map as R7)
    const int off0 = (kg == 0) ? 0  : (kg == 1) ? 8  : (kg == 2) ? 28 : 36;
    const int off1 = (kg == 0) ? 16 : (kg == 1) ? 20 : (kg == 2) ? 44 : 48;
    const float* pA0 = xrA + off0;
    const float* pA1 = xrA + off1;
    const float* pB0 = xrB + off0;
    const float* pB1 = xrB + off1;

    // preload my 14 W-fragments (56 VGPR), shared by both tiles
    const char* wbp = wsb + kh * 14336 + l * 16;
    const short8 wf0  = *(const short8*)(wbp + 0  * 1024);
    const short8 wf1  = *(const short8*)(wbp + 1  * 1024);
    const short8 wf2  = *(const short8*)(wbp + 2  * 1024);
    const short8 wf3  = *(const short8*)(wbp + 3  * 1024);
    const short8 wf4  = *(const short8*)(wbp + 4  * 1024);
    const short8 wf5  = *(const short8*)(wbp + 5  * 1024);
    const short8 wf6  = *(const short8*)(wbp + 6  * 1024);
    const short8 wf7  = *(const short8*)(wbp + 7  * 1024);
    const short8 wf8  = *(const short8*)(wbp + 8  * 1024);
    const short8 wf9  = *(const short8*)(wbp + 9  * 1024);
    const short8 wf10 = *(const short8*)(wbp + 10 * 1024);
    const short8 wf11 = *(const short8*)(wbp + 11 * 1024);
    const short8 wf12 = *(const short8*)(wbp + 12 * 1024);
    const short8 wf13 = *(const short8*)(wbp + 13 * 1024);

    f32x4 accA = {0.f, 0.f, 0.f, 0.f};
    f32x4 accB = {0.f, 0.f, 0.f, 0.f};

    // 7 patch-rows x 2 halves, fully unrolled, imm offsets
    QKB2(pA0, pB0, 0 * 56, wf0);  QKB2(pA1, pB1, 0 * 56, wf1);
    QKB2(pA0, pB0, 1 * 56, wf2);  QKB2(pA1, pB1, 1 * 56, wf3);
    QKB2(pA0, pB0, 2 * 56, wf4);  QKB2(pA1, pB1, 2 * 56, wf5);
    QKB2(pA0, pB0, 3 * 56, wf6);  QKB2(pA1, pB1, 3 * 56, wf7);
    QKB2(pA0, pB0, 4 * 56, wf8);  QKB2(pA1, pB1, 4 * 56, wf9);
    QKB2(pA0, pB0, 5 * 56, wf10); QKB2(pA1, pB1, 5 * 56, wf11);
    QKB2(pA0, pB0, 6 * 56, wf12); QKB2(pA1, pB1, 6 * 56, wf13);

    // ---- merge K-halves via LDS ----
    if (kh == 1) { red[0][l] = accA; red[1][l] = accB; }
    __syncthreads();
    if (kh == 0) {
        const f32x4 oA = red[0][l];
        const f32x4 oB = red[1][l];
#pragma unroll
        for (int j = 0; j < 4; ++j) { accA[j] += oA[j]; accB[j] += oB[j]; }

        // ---- epilogue x2: lane holds D[m=4*kg+j][n=r16] ----
        const float bn = bias[r16 < 10 ? r16 : 0];
#pragma unroll
        for (int tile = 0; tile < 2; ++tile) {
            const f32x4 a = tile ? accB : accA;
            const int rb  = blockIdx.x * 32 + tile * 16;
#pragma unroll
            for (int j = 0; j < 4; ++j) {
                float v = (r16 < 10) ? (a[j] + bn) : -1e30f;
                float mx = v;
                mx = fmaxf(mx, __shfl_xor(mx, 1, 64));
                mx = fmaxf(mx, __shfl_xor(mx, 2, 64));
                mx = fmaxf(mx, __shfl_xor(mx, 4, 64));
                mx = fmaxf(mx, __shfl_xor(mx, 8, 64));
                float e = (r16 < 10) ? __expf(v - mx) : 0.f;
                float s = e;
                s += __shfl_xor(s, 1, 64);
                s += __shfl_xor(s, 2, 64);
                s += __shfl_xor(s, 4, 64);
                s += __shfl_xor(s, 8, 64);
                const float ls = __logf(s) + mx;
                if (r16 < 10)
                    out[(size_t)(rb + 4 * kg + j) * 10 + r16] = v - ls;
            }
        }
    }
}

extern "C" void kernel_launch(void* const* d_in, const int* in_sizes, int n_in,
                              void* d_out, int out_size, void* d_ws, size_t ws_size,
                              hipStream_t stream) {
    const float* x    = (const float*)d_in[0];   // [65536, 784]
    const float* Wm   = (const float*)d_in[1];   // [10, 784]
    const float* bias = (const float*)d_in[2];   // [10]
    float* out        = (float*)d_out;           // [65536, 10]

    quanv_wprep_kernel<<<dim3(28), dim3(256), 0, stream>>>(
        Wm, (uint32_t*)d_ws);
    quanv_mfma4_kernel<<<dim3(2048), dim3(128), 0, stream>>>(
        x, (const char*)d_ws, bias, out);
}

// Round 10
// 42.680 us; speedup vs baseline: 1.1857x; 1.1857x over previous
//
#include <hip/hip_runtime.h>
#include <hip/hip_bf16.h>
#include <stdint.h>

// Quanvolution + linear(784->10) + log_softmax via MFMA, B=65536, fp32 in/out.
// R9: granule-exact loads. K-slots follow RAW x order: K-block kt covers row
// bytes [128kt, 128kt+128); lane (r16,kg) loads float4 at +16kg and +64+16kg.
// Every wave-instr touches exactly 16 x 64B granules (one per row), fully
// consumed, never re-touched -> 49-granule/row floor (R7 was ~84).
// Works because every even float pair (j,j+1) is the top- or bottom-pair of
// exactly one 2x2 patch (image rows have even length 28):
//   ri=j/28, pc=(j%28)/2, pr=ri/2; ri even -> features (p,0),(p,1);
//   ri odd -> (p,2),(p,3). Same FEAT8 formula as R7 (validated).
// W baked to bf16 frags ws[25][64][8] (25 KB); slots jp>=784 get W=0.
// kt=24 second load is clamped to row start (in-bounds garbage x W=0).
// Structure: 2048 blocks x 256 thr (rg x kh waves), 32 rows/block,
// kh=0: kt 0..12 (13 frags), kh=1: kt 13..24 (12 frags); 1 barrier.

typedef __attribute__((ext_vector_type(8))) short short8;
typedef __attribute__((ext_vector_type(4))) float f32x4;

// ---- pre-kernel: bake W -> bf16 frags ws[kt][lane][e], 25 KB ----
__global__ void quanv_wprep_kernel(const float* __restrict__ Wm,
                                   uint32_t* __restrict__ ws) {
    const int idx = blockIdx.x * 256 + threadIdx.x;   // [0, 6400)
    if (idx >= 6400) return;
    const int kt  = idx >> 8;       // 0..24
    const int rem = idx & 255;
    const int l   = rem >> 2;       // lane 0..63
    const int d   = rem & 3;        // u32 -> e = 2d, 2d+1
    const int n   = l & 15;
    const int kg  = l >> 4;
    uint32_t outv = 0;
    if (n < 10) {
        uint32_t hv[2];
#pragma unroll
        for (int d2 = 0; d2 < 2; ++d2) {
            const int e  = 2 * d + d2;
            // pair base float index for this slot
            const int jp = 32 * kt + 4 * kg + 16 * (e >> 2) + 2 * ((e >> 1) & 1);
            float v = 0.f;
            if (jp < 784) {
                const int ri = jp / 28;          // image row
                const int pc = (jp % 28) >> 1;   // patch col
                const int pr = ri >> 1;          // patch row
                const int ho = ri & 1;           // 0=top pair, 1=bottom pair
                const int col = (pr * 14 + pc) * 4 + 2 * ho + (e & 1);
                v = Wm[n * 784 + col];
            }
            hv[d2] = (uint32_t)__bfloat16_as_ushort(__float2bfloat16(v));
        }
        outv = hv[0] | (hv[1] << 16);
    }
    ws[idx] = outv;
}

// ---- 8 features from two float4s (pairs (x,y),(z,w) each) ----
#define FEAT8(VA, VB, A) do {                                                 \
    { const float ce=__cosf((VA).x), co=__cosf((VA).y);                       \
      (A)[0]=(short)__bfloat16_as_ushort(__float2bfloat16(ce + (VA).x));      \
      (A)[1]=(short)__bfloat16_as_ushort(__float2bfloat16(fmaf(ce,co,(VA).y)));}\
    { const float ce=__cosf((VA).z), co=__cosf((VA).w);                       \
      (A)[2]=(short)__bfloat16_as_ushort(__float2bfloat16(ce + (VA).z));      \
      (A)[3]=(short)__bfloat16_as_ushort(__float2bfloat16(fmaf(ce,co,(VA).w)));}\
    { const float ce=__cosf((VB).x), co=__cosf((VB).y);                       \
      (A)[4]=(short)__bfloat16_as_ushort(__float2bfloat16(ce + (VB).x));      \
      (A)[5]=(short)__bfloat16_as_ushort(__float2bfloat16(fmaf(ce,co,(VB).y)));}\
    { const float ce=__cosf((VB).z), co=__cosf((VB).w);                       \
      (A)[6]=(short)__bfloat16_as_ushort(__float2bfloat16(ce + (VB).z));      \
      (A)[7]=(short)__bfloat16_as_ushort(__float2bfloat16(fmaf(ce,co,(VB).w)));}\
} while (0)

// ---- one K-block: 2 granule-dense float4 loads -> 8 features -> 1 MFMA ----
#define QKB(KT, WF) do {                                                      \
    const float4 va = *(const float4*)(px + 32 * (KT));                       \
    const float4 vb = *(const float4*)(px + 32 * (KT) + 16);                  \
    short8 a; FEAT8(va, vb, a);                                               \
    acc = __builtin_amdgcn_mfma_f32_16x16x32_bf16(a, (WF), acc, 0, 0, 0);     \
} while (0)

__global__ __launch_bounds__(256, 4)
void quanv_mfma5_kernel(const float* __restrict__ x,
                        const char* __restrict__ wsb,   // bf16 frags [25][64][8]
                        const float* __restrict__ bias,
                        float* __restrict__ out) {
    __shared__ f32x4 red[2][64];   // 2 KB

    const int t   = threadIdx.x;
    const int l   = t & 63;
    const int w   = t >> 6;
    const int rg  = __builtin_amdgcn_readfirstlane(w >> 1);   // row-group 0/1
    const int kh  = __builtin_amdgcn_readfirstlane(w & 1);    // K-half 0/1
    const int r16 = l & 15;
    const int kg  = l >> 4;
    const int rowBase = blockIdx.x * 32 + rg * 16;
    const float* px = x + (size_t)(rowBase + r16) * 784 + 4 * kg;

    f32x4 acc = {0.f, 0.f, 0.f, 0.f};

    if (kh == 0) {
        const char* wbp = wsb + l * 16;
        const short8 wf0  = *(const short8*)(wbp + 0  * 1024);
        const short8 wf1  = *(const short8*)(wbp + 1  * 1024);
        const short8 wf2  = *(const short8*)(wbp + 2  * 1024);
        const short8 wf3  = *(const short8*)(wbp + 3  * 1024);
        const short8 wf4  = *(const short8*)(wbp + 4  * 1024);
        const short8 wf5  = *(const short8*)(wbp + 5  * 1024);
        const short8 wf6  = *(const short8*)(wbp + 6  * 1024);
        const short8 wf7  = *(const short8*)(wbp + 7  * 1024);
        const short8 wf8  = *(const short8*)(wbp + 8  * 1024);
        const short8 wf9  = *(const short8*)(wbp + 9  * 1024);
        const short8 wf10 = *(const short8*)(wbp + 10 * 1024);
        const short8 wf11 = *(const short8*)(wbp + 11 * 1024);
        const short8 wf12 = *(const short8*)(wbp + 12 * 1024);
        QKB(0, wf0);  QKB(1, wf1);  QKB(2, wf2);  QKB(3, wf3);
        QKB(4, wf4);  QKB(5, wf5);  QKB(6, wf6);  QKB(7, wf7);
        QKB(8, wf8);  QKB(9, wf9);  QKB(10, wf10); QKB(11, wf11);
        QKB(12, wf12);
    } else {
        const char* wbp = wsb + 13 * 1024 + l * 16;
        const short8 wf0  = *(const short8*)(wbp + 0  * 1024);
        const short8 wf1  = *(const short8*)(wbp + 1  * 1024);
        const short8 wf2  = *(const short8*)(wbp + 2  * 1024);
        const short8 wf3  = *(const short8*)(wbp + 3  * 1024);
        const short8 wf4  = *(const short8*)(wbp + 4  * 1024);
        const short8 wf5  = *(const short8*)(wbp + 5  * 1024);
        const short8 wf6  = *(const short8*)(wbp + 6  * 1024);
        const short8 wf7  = *(const short8*)(wbp + 7  * 1024);
        const short8 wf8  = *(const short8*)(wbp + 8  * 1024);
        const short8 wf9  = *(const short8*)(wbp + 9  * 1024);
        const short8 wf10 = *(const short8*)(wbp + 10 * 1024);
        const short8 wf11 = *(const short8*)(wbp + 11 * 1024);
        QKB(13, wf0);  QKB(14, wf1);  QKB(15, wf2);  QKB(16, wf3);
        QKB(17, wf4);  QKB(18, wf5);  QKB(19, wf6);  QKB(20, wf7);
        QKB(21, wf8);  QKB(22, wf9);  QKB(23, wf10);
        {   // kt = 24: second quad would cross row end -> clamp in-bounds;
            // its slots (jp >= 784) have W = 0, value irrelevant.
            const float4 va = *(const float4*)(px + 32 * 24);
            const float4 vb = *(const float4*)(px);
            short8 a; FEAT8(va, vb, a);
            acc = __builtin_amdgcn_mfma_f32_16x16x32_bf16(a, wf11, acc, 0, 0, 0);
        }
    }

    // ---- merge K-halves via LDS ----
    if (kh == 1) red[rg][l] = acc;
    __syncthreads();
    if (kh == 0) {
        const f32x4 o = red[rg][l];
#pragma unroll
        for (int j = 0; j < 4; ++j) acc[j] += o[j];

        // ---- epilogue: lane holds D[m=4*kg+j][n=r16]; log_softmax over n ----
        const float bn = bias[r16 < 10 ? r16 : 0];
#pragma unroll
        for (int j = 0; j < 4; ++j) {
            float v = (r16 < 10) ? (acc[j] + bn) : -1e30f;
            float mx = v;
            mx = fmaxf(mx, __shfl_xor(mx, 1, 64));
            mx = fmaxf(mx, __shfl_xor(mx, 2, 64));
            mx = fmaxf(mx, __shfl_xor(mx, 4, 64));
            mx = fmaxf(mx, __shfl_xor(mx, 8, 64));
            float e = (r16 < 10) ? __expf(v - mx) : 0.f;
            float s = e;
            s += __shfl_xor(s, 1, 64);
            s += __shfl_xor(s, 2, 64);
            s += __shfl_xor(s, 4, 64);
            s += __shfl_xor(s, 8, 64);
            const float ls = __logf(s) + mx;
            if (r16 < 10)
                out[(size_t)(rowBase + 4 * kg + j) * 10 + r16] = v - ls;
        }
    }
}

extern "C" void kernel_launch(void* const* d_in, const int* in_sizes, int n_in,
                              void* d_out, int out_size, void* d_ws, size_t ws_size,
                              hipStream_t stream) {
    const float* x    = (const float*)d_in[0];   // [65536, 784]
    const float* Wm   = (const float*)d_in[1];   // [10, 784]
    const float* bias = (const float*)d_in[2];   // [10]
    float* out        = (float*)d_out;           // [65536, 10]

    quanv_wprep_kernel<<<dim3(25), dim3(256), 0, stream>>>(
        Wm, (uint32_t*)d_ws);
    quanv_mfma5_kernel<<<dim3(2048), dim3(256), 0, stream>>>(
        x, (const char*)d_ws, bias, out);
}

// Round 11
// 39.997 us; speedup vs baseline: 1.2652x; 1.0671x over previous
//
#include <hip/hip_runtime.h>
#include <hip/hip_bf16.h>
#include <stdint.h>

// Quanvolution + linear(784->10) + log_softmax via MFMA, B=65536, fp32 in/out.
// R10: R9's granule-exact K-order (validated) + 4-way K-split with EXPLICIT
// full load hoist: each wave owns a K-quarter (6-7 K-blocks) and issues ALL
// its x-loads (12-14 float4) and W-frags before any compute -> one latency
// exposure per wave instead of a partially-serialized 13-deep chain.
//  - 4096 blocks x 256 thr; block = 16 rows; wave kq = K-quarter.
//    kq0: kt 0-6, kq1: 7-12, kq2: 13-18, kq3: 19-24 (incl. clamped kt24).
//  - all load/compute indices compile-time (template + full unroll) -> regs.
//  - merge 4 partial accs via 3KB LDS, 1 barrier; kq0 does epilogue.
// K-slot map (validated R9): K-block kt covers row bytes [128kt,128kt+128);
// lane (r16,kg) loads float4 at +16kg and +64+16kg; every even float pair
// (j,j+1) is a top/bottom pair of one patch; pads (jp>=784) have W=0.

typedef __attribute__((ext_vector_type(8))) short short8;
typedef __attribute__((ext_vector_type(4))) float f32x4;

// ---- pre-kernel: bake W -> bf16 frags ws[kt][lane][e], 25 KB ----
__global__ void quanv_wprep_kernel(const float* __restrict__ Wm,
                                   uint32_t* __restrict__ ws) {
    const int idx = blockIdx.x * 256 + threadIdx.x;   // [0, 6400)
    if (idx >= 6400) return;
    const int kt  = idx >> 8;       // 0..24
    const int rem = idx & 255;
    const int l   = rem >> 2;       // lane 0..63
    const int d   = rem & 3;        // u32 -> e = 2d, 2d+1
    const int n   = l & 15;
    const int kg  = l >> 4;
    uint32_t outv = 0;
    if (n < 10) {
        uint32_t hv[2];
#pragma unroll
        for (int d2 = 0; d2 < 2; ++d2) {
            const int e  = 2 * d + d2;
            const int jp = 32 * kt + 4 * kg + 16 * (e >> 2) + 2 * ((e >> 1) & 1);
            float v = 0.f;
            if (jp < 784) {
                const int ri = jp / 28;          // image row
                const int pc = (jp % 28) >> 1;   // patch col
                const int pr = ri >> 1;          // patch row
                const int ho = ri & 1;           // 0=top pair, 1=bottom pair
                const int col = (pr * 14 + pc) * 4 + 2 * ho + (e & 1);
                v = Wm[n * 784 + col];
            }
            hv[d2] = (uint32_t)__bfloat16_as_ushort(__float2bfloat16(v));
        }
        outv = hv[0] | (hv[1] << 16);
    }
    ws[idx] = outv;
}

// ---- 8 features from two float4s (pairs (x,y),(z,w) each) ----
#define FEAT8(VA, VB, A) do {                                                 \
    { const float ce=__cosf((VA).x), co=__cosf((VA).y);                       \
      (A)[0]=(short)__bfloat16_as_ushort(__float2bfloat16(ce + (VA).x));      \
      (A)[1]=(short)__bfloat16_as_ushort(__float2bfloat16(fmaf(ce,co,(VA).y)));}\
    { const float ce=__cosf((VA).z), co=__cosf((VA).w);                       \
      (A)[2]=(short)__bfloat16_as_ushort(__float2bfloat16(ce + (VA).z));      \
      (A)[3]=(short)__bfloat16_as_ushort(__float2bfloat16(fmaf(ce,co,(VA).w)));}\
    { const float ce=__cosf((VB).x), co=__cosf((VB).y);                       \
      (A)[4]=(short)__bfloat16_as_ushort(__float2bfloat16(ce + (VB).x));      \
      (A)[5]=(short)__bfloat16_as_ushort(__float2bfloat16(fmaf(ce,co,(VB).y)));}\
    { const float ce=__cosf((VB).z), co=__cosf((VB).w);                       \
      (A)[6]=(short)__bfloat16_as_ushort(__float2bfloat16(ce + (VB).z));      \
      (A)[7]=(short)__bfloat16_as_ushort(__float2bfloat16(fmaf(ce,co,(VB).w)));}\
} while (0)

// ---- one K-quarter: issue ALL loads, then compute (full static unroll) ----
template <int KT0, int N>
__device__ __forceinline__ void quarter(const float* __restrict__ px,
                                        const char* __restrict__ wsb,
                                        int l, f32x4& acc) {
    float4 va[N], vb[N];
    short8 wf[N];
    const char* wbp = wsb + KT0 * 1024 + l * 16;
#pragma unroll
    for (int j = 0; j < N; ++j) {
        const int kt = KT0 + j;
        va[j] = *(const float4*)(px + 32 * kt);
        // kt=24 second quad would cross the row end -> clamp (W=0 kills it)
        vb[j] = (kt == 24) ? *(const float4*)(px)
                           : *(const float4*)(px + 32 * kt + 16);
        wf[j] = *(const short8*)(wbp + j * 1024);
    }
#pragma unroll
    for (int j = 0; j < N; ++j) {
        short8 a;
        FEAT8(va[j], vb[j], a);
        acc = __builtin_amdgcn_mfma_f32_16x16x32_bf16(a, wf[j], acc, 0, 0, 0);
    }
}

__global__ __launch_bounds__(256, 4)
void quanv_mfma6_kernel(const float* __restrict__ x,
                        const char* __restrict__ wsb,   // bf16 frags [25][64][8]
                        const float* __restrict__ bias,
                        float* __restrict__ out) {
    __shared__ f32x4 red[3][64];   // 3 KB: kq=1..3 accumulators

    const int t   = threadIdx.x;
    const int l   = t & 63;
    const int kq  = __builtin_amdgcn_readfirstlane(t >> 6);   // K-quarter 0..3
    const int r16 = l & 15;
    const int kg  = l >> 4;
    const int rowBase = blockIdx.x * 16;
    const float* px = x + (size_t)(rowBase + r16) * 784 + 4 * kg;

    f32x4 acc = {0.f, 0.f, 0.f, 0.f};

    if      (kq == 0) quarter<0, 7>(px, wsb, l, acc);
    else if (kq == 1) quarter<7, 6>(px, wsb, l, acc);
    else if (kq == 2) quarter<13, 6>(px, wsb, l, acc);
    else              quarter<19, 6>(px, wsb, l, acc);

    // ---- merge K-quarters via LDS ----
    if (kq != 0) red[kq - 1][l] = acc;
    __syncthreads();
    if (kq == 0) {
#pragma unroll
        for (int s = 0; s < 3; ++s) {
            const f32x4 o = red[s][l];
#pragma unroll
            for (int j = 0; j < 4; ++j) acc[j] += o[j];
        }

        // ---- epilogue: lane holds D[m=4*kg+j][n=r16]; log_softmax over n ----
        const float bn = bias[r16 < 10 ? r16 : 0];
#pragma unroll
        for (int j = 0; j < 4; ++j) {
            float v = (r16 < 10) ? (acc[j] + bn) : -1e30f;
            float mx = v;
            mx = fmaxf(mx, __shfl_xor(mx, 1, 64));
            mx = fmaxf(mx, __shfl_xor(mx, 2, 64));
            mx = fmaxf(mx, __shfl_xor(mx, 4, 64));
            mx = fmaxf(mx, __shfl_xor(mx, 8, 64));
            float e = (r16 < 10) ? __expf(v - mx) : 0.f;
            float s = e;
            s += __shfl_xor(s, 1, 64);
            s += __shfl_xor(s, 2, 64);
            s += __shfl_xor(s, 4, 64);
            s += __shfl_xor(s, 8, 64);
            const float ls = __logf(s) + mx;
            if (r16 < 10)
                out[(size_t)(rowBase + 4 * kg + j) * 10 + r16] = v - ls;
        }
    }
}

extern "C" void kernel_launch(void* const* d_in, const int* in_sizes, int n_in,
                              void* d_out, int out_size, void* d_ws, size_t ws_size,
                              hipStream_t stream) {
    const float* x    = (const float*)d_in[0];   // [65536, 784]
    const float* Wm   = (const float*)d_in[1];   // [10, 784]
    const float* bias = (const float*)d_in[2];   // [10]
    float* out        = (float*)d_out;           // [65536, 10]

    quanv_wprep_kernel<<<dim3(25), dim3(256), 0, stream>>>(
        Wm, (uint32_t*)d_ws);
    quanv_mfma6_kernel<<<dim3(4096), dim3(256), 0, stream>>>(
        x, (const char*)d_ws, bias, out);
}